// Round 7
// baseline (265.622 us; speedup 1.0000x reference)
//
#include <hip/hip_runtime.h>
#include <hip/hip_bf16.h>
#include <math.h>

// Problem constants
#define BATCH 32
#define CIN   256
#define HIN   28
#define WIN   28
#define NPROT 1024
#define HOUT  26
#define WOUT  26
#define MTOT  (BATCH*HOUT*WOUT)   // 21632 = 169*128
#define HWIN  (HIN*WIN)           // 784
#define KTOT  (CIN*9)             // 2304
#define NKT   36                  // K-tiles of 64: 9 taps x 4 chunks

typedef __attribute__((ext_vector_type(8))) short short8;
typedef __attribute__((ext_vector_type(4))) float f32x4;

// ---- workspace layout (bytes) ----
#define OFF_XT  ((size_t)0)
#define OFF_PTT ((size_t)12845056)
#define OFF_S   ((size_t)17563648)
#define OFF_PSQ ((size_t)17664000)
#define WS_NEED ((size_t)17668096)

__device__ __forceinline__ void gload16(const void* g, void* l) {
    __builtin_amdgcn_global_load_lds((__attribute__((address_space(1))) void*)g,
                                     (__attribute__((address_space(3))) void*)l,
                                     16, 0, 0);
}

// ---- P1: x NCHW fp32 -> NHWC bf16, plus per-pixel sum of squares ----
__global__ void xpose_kernel(const float* __restrict__ x,
                             __hip_bfloat16* __restrict__ xT,
                             float* __restrict__ s) {
    __shared__ float tile[32][33];
    const int b = blockIdx.z, hw0 = blockIdx.x * 32;
    const int tx = threadIdx.x, ty = threadIdx.y;  // block (32,8)
    const float* xb = x + (size_t)b * CIN * HWIN;
    float ssacc = 0.f;
    for (int cg = 0; cg < 8; ++cg) {
        const int c0 = cg * 32;
        __syncthreads();
        for (int q = 0; q < 4; ++q) {
            int c = c0 + ty + q * 8, hw = hw0 + tx;
            float v = (hw < HWIN) ? xb[c * HWIN + hw] : 0.f;
            tile[ty + q * 8][tx] = v;
        }
        __syncthreads();
        for (int rq = 0; rq < 4; ++rq) {
            float v = tile[ty + rq * 8][tx];
            ssacc += v * v;
        }
        for (int q = 0; q < 4; ++q) {
            int hw = hw0 + ty + q * 8, c = c0 + tx;
            if (hw < HWIN)
                xT[((size_t)b * HWIN + hw) * CIN + c] = __float2bfloat16(tile[tx][ty + q * 8]);
        }
    }
    __syncthreads();
    tile[ty][tx] = ssacc;
    __syncthreads();
    if (ty == 0) {
        int hw = hw0 + tx;
        if (hw < HWIN) {
            float a = 0.f;
            for (int r = 0; r < 8; ++r) a += tile[r][tx];
            s[b * HWIN + hw] = a;
        }
    }
}

// ---- P2: prototypes OIHW fp32 -> [tap][p][c] bf16, plus ||p||^2 ----
__global__ void ppose_kernel(const float* __restrict__ proto,
                             __hip_bfloat16* __restrict__ pTT,
                             float* __restrict__ psq) {
    const int p = blockIdx.x, c = threadIdx.x;
    const float* pp = proto + ((size_t)p * CIN + c) * 9;
    float v[9]; float ss = 0.f;
    for (int t = 0; t < 9; ++t) { v[t] = pp[t]; ss += v[t] * v[t]; }
    for (int t = 0; t < 9; ++t)
        pTT[((size_t)t * NPROT + p) * CIN + c] = __float2bfloat16(v[t]);
    for (int o = 32; o > 0; o >>= 1) ss += __shfl_down(ss, o, 64);
    __shared__ float red[4];
    if ((c & 63) == 0) red[c >> 6] = ss;
    __syncthreads();
    if (c == 0) psq[p] = red[0] + red[1] + red[2] + red[3];
}

// ---- G: implicit-GEMM bf16 MFMA, K-HALF-PLANE COUNTED pipeline.
// D[p][m] = sum_k proto[p][k] * patch[m][k]
// Tile: 256(p) x 128(m) x BK=64. 8 waves (4p x 2m); per-wave 64x64 via
// 4x4 16x16x32 frags -- fragment/epilogue math IDENTICAL to the verified
// round-3 kernel, only wave-grid constants differ.
// LDS per buffer: K-half planes Ak0[256][32] Ak1[256][32] Bk0[128][32]
// Bk1[128][32] bf16 = 48KB; 2 buffers = 96KB -> 1 block/CU (8 waves).
// Schedule (the counted-vmcnt fix for the 2-buffer drain):
//   tile kt, buf b=kt&1:
//   P0: ds_read plane0(b) frags; issue stage plane0(kt+1 -> b^1) [3 gloads];
//       16 MFMA (ks=0); vmcnt(3); s_barrier.
//   P1: ds_read plane1(b); issue stage plane1(kt+1); 16 MFMA (ks=1);
//       vmcnt(3); s_barrier.
// Invariant: each vmcnt(3) leaves ONLY the 3 just-issued loads in flight
// and ratchets the 2-phase-old half-plane (~1200cy of cover > ~900cy HBM
// latency) to completion -> no wait in the steady loop ever drains young
// loads. This is T3+T4 with 2 buffers; avoids R2's failure modes (waits on
// 1-phase-old loads, 4 barriers/tile, 144KB).
// Swizzle (64B plane rows, 4 granules): store slot = g ^ (row&3); read
// slot = quad ^ (l15&3). 8-lane service groups hit >=4 distinct 16B
// granule-banks (<=2-way, free per m136); both sides same involution.
__global__ __launch_bounds__(512, 1)
void gemm_kernel(const __hip_bfloat16* __restrict__ xT,
                 const __hip_bfloat16* __restrict__ pTT,
                 const float* __restrict__ s,
                 const float* __restrict__ psq,
                 float* __restrict__ out) {
    // element offsets within a buffer: Ak0 @0, Ak1 @8192, Bk0 @16384, Bk1 @20480
    __shared__ __hip_bfloat16 lds[2][24576];   // 96 KB
    const int tid = threadIdx.x, wave = tid >> 6, lane = tid & 63;
    const int n0 = blockIdx.x * 128;  // m tile base (169 tiles, exact)
    const int m0 = blockIdx.y * 256;  // p tile base (4 tiles, exact)

    // ---- staging source precompute ----
    // Each gload16 call-site: 8 waves x 64 lanes x 16B = 128 rows of 64B.
    // lane l -> row sub = l>>2, granule slot = l&3, source granule
    // g_src = (l&3) ^ ((l>>2)&3)  (row&3 == (l>>2)&3 since bases %4==0).
    const int rsub = lane >> 2;
    const int gsrc = (lane & 3) ^ (rsub & 3);
    int asrc[2], bsrc;
#pragma unroll
    for (int c = 0; c < 2; ++c) {
        int row = c * 128 + wave * 16 + rsub;        // A row in [0,256)
        asrc[c] = (m0 + row) * CIN + gsrc * 8;
    }
    {
        int rowb = wave * 16 + rsub;                 // B row in [0,128)
        int mm = n0 + rowb;
        int bb = mm / 676, rr = mm % 676, ii = rr / WOUT, jj = rr % WOUT;
        bsrc = (bb * HWIN + ii * WIN + jj) * CIN + gsrc * 8;
    }

    // stage half-plane h of K-tile kt into buffer buf: 3 gloads per wave
    auto stage = [&](int kt, int h, int buf) {
        const int tap = kt >> 2, cc = (kt & 3) * 64 + h * 32;
        const __hip_bfloat16* srcP = pTT + (size_t)tap * (NPROT * CIN) + cc;
        const __hip_bfloat16* srcX = xT + ((tap / 3) * WIN + (tap % 3)) * CIN + cc;
        __hip_bfloat16* base = &lds[buf][0];
        gload16(srcP + asrc[0], base + h * 8192 + (wave * 16) * 32);
        gload16(srcP + asrc[1], base + h * 8192 + (128 + wave * 16) * 32);
        gload16(srcX + bsrc,    base + 16384 + h * 4096 + (wave * 16) * 32);
    };

    f32x4 acc[4][4];
#pragma unroll
    for (int a = 0; a < 4; ++a)
#pragma unroll
        for (int b = 0; b < 4; ++b) acc[a][b] = (f32x4){0.f, 0.f, 0.f, 0.f};

    const int wr = wave >> 1, wc = wave & 1;   // 4 p-rows x 2 m-cols of waves
    const int quad = lane >> 4, l15 = lane & 15;
    const int kc = (quad ^ (l15 & 3)) * 8;     // swizzled granule slot (8 elts)

    // prologue: stage both halves of tile 0; wait for half 0 only.
    stage(0, 0, 0);
    stage(0, 1, 0);
    asm volatile("s_waitcnt vmcnt(3)" ::: "memory");
    __builtin_amdgcn_s_barrier();

#pragma unroll 2
    for (int kt = 0; kt < NKT; ++kt) {
        const int b = kt & 1;
        const bool st = (kt + 1) < NKT;
#pragma unroll
        for (int ks = 0; ks < 2; ++ks) {
            const __hip_bfloat16* Ap = &lds[b][ks * 8192];
            const __hip_bfloat16* Bp = &lds[b][16384 + ks * 4096];
            short8 af[4], bf[4];
#pragma unroll
            for (int im = 0; im < 4; ++im)
                af[im] = *(const short8*)&Ap[(wr * 64 + im * 16 + l15) * 32 + kc];
#pragma unroll
            for (int in = 0; in < 4; ++in)
                bf[in] = *(const short8*)&Bp[(wc * 64 + in * 16 + l15) * 32 + kc];

            if (st) stage(kt + 1, ks, b ^ 1);   // half-plane ks of next tile

            __builtin_amdgcn_s_setprio(1);
#pragma unroll
            for (int im = 0; im < 4; ++im)
#pragma unroll
                for (int in = 0; in < 4; ++in)
                    acc[im][in] = __builtin_amdgcn_mfma_f32_16x16x32_bf16(
                        af[im], bf[in], acc[im][in], 0, 0, 0);
            __builtin_amdgcn_s_setprio(0);

            if (kt + 1 < NKT) {
                // counted: leave only the 3 loads issued THIS phase in
                // flight; forces the 2-phase-old half-plane complete.
                asm volatile("s_waitcnt vmcnt(3)" ::: "memory");
                __builtin_amdgcn_s_barrier();
            } else if (ks == 0) {
                // last tile: plane1 was issued 2 phases ago; drain cheap.
                asm volatile("s_waitcnt vmcnt(0)" ::: "memory");
                __builtin_amdgcn_s_barrier();
            }
        }
    }

    // epilogue: out[b][p][i][j] = sqrt(clip(s3 - 2C + psq)), s3 = 3x3 box of s
    // (identical to verified round-3 epilogue; wr now spans 4 -> p covers 256)
#pragma unroll
    for (int in = 0; in < 4; ++in) {
        int mm = n0 + wc * 64 + in * 16 + l15;
        int bb = mm / 676, rr = mm % 676, ii = rr / WOUT, jj = rr % WOUT;
        const float* sb = s + bb * HWIN + ii * WIN + jj;
        float s3v = 0.f;
#pragma unroll
        for (int di = 0; di < 3; ++di)
#pragma unroll
            for (int dj = 0; dj < 3; ++dj) s3v += sb[di * WIN + dj];
        float* ob = out + (size_t)bb * (NPROT * 676) + rr;
#pragma unroll
        for (int im = 0; im < 4; ++im) {
            int pbase_ = m0 + wr * 64 + im * 16 + quad * 4;
#pragma unroll
            for (int r = 0; r < 4; ++r) {
                int p = pbase_ + r;
                float d2 = s3v - 2.f * acc[im][in][r] + psq[p];
                ob[(size_t)p * 676] = sqrtf(fmaxf(d2, 1e-14f));
            }
        }
    }
}

// ---- fallback (only if ws too small): direct fp32 ----
__global__ void naive_kernel(const float* __restrict__ x,
                             const float* __restrict__ proto,
                             float* __restrict__ out) {
    __shared__ float patch[KTOT];
    int m = blockIdx.x;
    int b = m / 676, rr = m % 676, i = rr / WOUT, j = rr % WOUT;
    int c = threadIdx.x;
    const float* xb = x + (((size_t)b * CIN + c) * HIN + i) * WIN + j;
    for (int t = 0; t < 9; ++t) patch[c * 9 + t] = xb[(t / 3) * WIN + (t % 3)];
    __syncthreads();
    for (int pp = threadIdx.x; pp < NPROT; pp += 256) {
        const float* pr = proto + (size_t)pp * KTOT;
        float acc = 0.f;
        for (int k = 0; k < KTOT; ++k) { float d = patch[k] - pr[k]; acc += d * d; }
        out[((size_t)b * NPROT + pp) * 676 + rr] = sqrtf(fmaxf(acc, 1e-14f));
    }
}

extern "C" void kernel_launch(void* const* d_in, const int* in_sizes, int n_in,
                              void* d_out, int out_size, void* d_ws, size_t ws_size,
                              hipStream_t stream) {
    const float* x = (const float*)d_in[0];
    const float* proto = (const float*)d_in[1];
    float* out = (float*)d_out;

    if (ws_size < WS_NEED) {
        naive_kernel<<<MTOT, 256, 0, stream>>>(x, proto, out);
        return;
    }

    char* ws = (char*)d_ws;
    __hip_bfloat16* xT  = (__hip_bfloat16*)(ws + OFF_XT);
    __hip_bfloat16* pTT = (__hip_bfloat16*)(ws + OFF_PTT);
    float* s   = (float*)(ws + OFF_S);
    float* psq = (float*)(ws + OFF_PSQ);

    xpose_kernel<<<dim3(25, 1, BATCH), dim3(32, 8), 0, stream>>>(x, xT, s);
    ppose_kernel<<<NPROT, 256, 0, stream>>>(proto, pTT, psq);
    gemm_kernel<<<dim3(169, 4), 512, 0, stream>>>(xT, pTT, s, psq, out);
}

// Round 8
// 241.673 us; speedup vs baseline: 1.0991x; 1.0991x over previous
//
#include <hip/hip_runtime.h>
#include <hip/hip_bf16.h>
#include <math.h>

// Problem constants
#define BATCH 32
#define CIN   256
#define HIN   28
#define WIN   28
#define NPROT 1024
#define HOUT  26
#define WOUT  26
#define MTOT  (BATCH*HOUT*WOUT)   // 21632 = 169*128
#define HWIN  (HIN*WIN)           // 784
#define KTOT  (CIN*9)             // 2304
#define NKT   36                  // K-tiles of 64: 9 taps x 4 chunks

typedef __attribute__((ext_vector_type(8))) short short8;
typedef __attribute__((ext_vector_type(4))) float f32x4;

// ---- workspace layout (bytes) ----
#define OFF_XT  ((size_t)0)
#define OFF_PTT ((size_t)12845056)
#define OFF_S   ((size_t)17563648)
#define OFF_PSQ ((size_t)17664000)
#define WS_NEED ((size_t)17668096)

__device__ __forceinline__ void gload16(const void* g, void* l) {
    __builtin_amdgcn_global_load_lds((__attribute__((address_space(1))) void*)g,
                                     (__attribute__((address_space(3))) void*)l,
                                     16, 0, 0);
}

// ---- P1+P2 merged: one launch.
// blocks [0,800):   x NCHW fp32 -> NHWC bf16 (vectorized) + per-pixel sum-sq
// blocks [800,1824): prototypes OIHW fp32 -> [tap][p][c] bf16 + ||p||^2
__global__ __launch_bounds__(256)
void prep_kernel(const float* __restrict__ x, const float* __restrict__ proto,
                 __hip_bfloat16* __restrict__ xT, __hip_bfloat16* __restrict__ pTT,
                 float* __restrict__ s, float* __restrict__ psq) {
    const int bid = blockIdx.x;
    if (bid < 800) {
        // ---- xpose: 32 hw x 256 c tile per block ----
        // LDS tile fp32, [hw][c] with rotate-XOR granule swizzle:
        //   granule slot = (c>>3) ^ rot(hw),  rot(h) = ((h>>2)|(h<<3))&31
        // rot makes slot&3 vary with hw's bit-2..4 (the per-wave-varying
        // bits on both the write and read sides) -> <=2-way everywhere
        // (2-way is free, m136).
        __shared__ float tile[32 * 256];          // 32 KB
        __shared__ float red[32][33];             // per-(c mod 32) hw sums
        __shared__ float red2[8][33];
        const int tid = threadIdx.x;
        const int b = bid / 25, hw0 = (bid % 25) * 32;
        const int i = tid & 7, cr = tid >> 3;     // hw-quad, c-row
        const float* xb = x + (size_t)b * CIN * HWIN;
        const bool full = (hw0 + 32 <= HWIN);
        float sq[4] = {0.f, 0.f, 0.f, 0.f};
#pragma unroll
        for (int q = 0; q < 8; ++q) {
            const int c = q * 32 + cr;
            const int hw = hw0 + i * 4;
            float4 v;
            if (full) {
                v = *(const float4*)&xb[(size_t)c * HWIN + hw];
            } else {
                v.x = (hw + 0 < HWIN) ? xb[(size_t)c * HWIN + hw + 0] : 0.f;
                v.y = (hw + 1 < HWIN) ? xb[(size_t)c * HWIN + hw + 1] : 0.f;
                v.z = (hw + 2 < HWIN) ? xb[(size_t)c * HWIN + hw + 2] : 0.f;
                v.w = (hw + 3 < HWIN) ? xb[(size_t)c * HWIN + hw + 3] : 0.f;
            }
            const int cq = (c >> 3), c7 = c & 7;
            float vv[4] = {v.x, v.y, v.z, v.w};
#pragma unroll
            for (int d = 0; d < 4; ++d) {
                const int hwl = i * 4 + d;
                const int rot = ((hwl >> 2) | (hwl << 3)) & 31;
                tile[hwl * 256 + ((cq ^ rot) << 3) + c7] = vv[d];
                sq[d] += vv[d] * vv[d];
            }
        }
#pragma unroll
        for (int d = 0; d < 4; ++d) red[cr][i * 4 + d] = sq[d];
        __syncthreads();

        const int v2 = tid & 31, u = tid >> 5;
        {   // fold 32 c-row partials -> 8
            float part = 0.f;
#pragma unroll
            for (int j = 0; j < 4; ++j) part += red[u + 8 * j][v2];
            red2[u][v2] = part;
        }
        // bf16 NHWC writes: 16B per lane, 512B contiguous per hw row
#pragma unroll
        for (int w = 0; w < 4; ++w) {
            const int hwl = w * 8 + u;
            const int hw = hw0 + hwl;
            if (hw < HWIN) {
                const int rot = ((hwl >> 2) | (hwl << 3)) & 31;
                const float* g = &tile[hwl * 256 + ((v2 ^ rot) << 3)];
                float fa[8];
                *(float4*)&fa[0] = *(const float4*)g;
                *(float4*)&fa[4] = *(const float4*)(g + 4);
                short8 o;
#pragma unroll
                for (int k = 0; k < 8; ++k) {
                    __hip_bfloat16 hb = __float2bfloat16(fa[k]);
                    o[k] = *reinterpret_cast<short*>(&hb);
                }
                *(short8*)&xT[((size_t)b * HWIN + hw) * CIN + v2 * 8] = o;
            }
        }
        __syncthreads();
        if (u == 0) {
            const int hw = hw0 + v2;
            if (hw < HWIN) {
                float a = 0.f;
#pragma unroll
                for (int k = 0; k < 8; ++k) a += red2[k][v2];
                s[b * HWIN + hw] = a;
            }
        }
    } else {
        // ---- ppose ----
        const int p = bid - 800, c = threadIdx.x;
        const float* pp = proto + ((size_t)p * CIN + c) * 9;
        float v[9]; float ss = 0.f;
#pragma unroll
        for (int t = 0; t < 9; ++t) { v[t] = pp[t]; ss += v[t] * v[t]; }
#pragma unroll
        for (int t = 0; t < 9; ++t)
            pTT[((size_t)t * NPROT + p) * CIN + c] = __float2bfloat16(v[t]);
        for (int o = 32; o > 0; o >>= 1) ss += __shfl_down(ss, o, 64);
        __shared__ float redp[4];
        if ((c & 63) == 0) redp[c >> 6] = ss;
        __syncthreads();
        if (c == 0) psq[p] = redp[0] + redp[1] + redp[2] + redp[3];
    }
}

// ---- G: implicit-GEMM bf16 MFMA, 2-deep issue-early pipeline (R3 verbatim,
// the verified best: 142us gemm, SQ_LDS_BANK_CONFLICT == 0).
// D[p][m] = sum_k proto[p][k] * patch[m][k]
// Tile: 128(p) x 128(m) x BK=64. 4 waves (2x2), per-wave 64x64 via 4x4
// 16x16x32 fragments. LDS 2 x 32KB -> 2 blocks/CU.
// Per K-tile: issue kt+1's 8 global_load_lds FIRST, compute kt (16
// ds_read_b128 + 32 MFMA), then vmcnt(0) + barrier. 128B rows, swizzle
// slot = chunk ^ (row&7) on both sides (the only measured-zero pattern).
__global__ __launch_bounds__(256, 2)
void gemm_kernel(const __hip_bfloat16* __restrict__ xT,
                 const __hip_bfloat16* __restrict__ pTT,
                 const float* __restrict__ s,
                 const float* __restrict__ psq,
                 float* __restrict__ out) {
    __shared__ __hip_bfloat16 lds[2][16384];  // [buf][ A:0..8191 | B:8192..16383 ]
    const int tid = threadIdx.x, wave = tid >> 6, lane = tid & 63;
    const int n0 = blockIdx.x * 128;  // m (image-pos) tile base
    const int m0 = blockIdx.y * 128;  // p tile base
    const int lrow = lane >> 3;
    const int lcol = ((lane & 7) ^ lrow) * 8;   // pre-swizzled source chunk col

    int xbase[4], pbase[4];
#pragma unroll
    for (int q = 0; q < 4; ++q) {
        int rl = wave * 32 + q * 8 + lrow;
        int mm = n0 + rl;
        int bb = mm / 676, rr = mm % 676, ii = rr / WOUT, jj = rr % WOUT;
        xbase[q] = (bb * HWIN + ii * WIN + jj) * CIN + lcol;
        pbase[q] = (m0 + rl) * CIN + lcol;
    }

    auto stage = [&](int kt, int buf) {
        const int tap = kt >> 2, cc = (kt & 3) * 64;
        const __hip_bfloat16* srcP = pTT + (size_t)tap * (NPROT * CIN) + cc;
        const __hip_bfloat16* srcX = xT + ((tap / 3) * WIN + (tap % 3)) * CIN + cc;
        __hip_bfloat16* base = &lds[buf][0];
#pragma unroll
        for (int q = 0; q < 4; ++q) {
            gload16(srcP + pbase[q], base + (wave * 32 + q * 8) * 64);
            gload16(srcX + xbase[q], base + 8192 + (wave * 32 + q * 8) * 64);
        }
    };

    f32x4 acc[4][4];
#pragma unroll
    for (int a = 0; a < 4; ++a)
#pragma unroll
        for (int b = 0; b < 4; ++b) acc[a][b] = (f32x4){0.f, 0.f, 0.f, 0.f};

    const int wr = wave >> 1, wc = wave & 1;   // wave 2x2: wr->p dir, wc->m dir
    const int quad = lane >> 4, l15 = lane & 15;
    const int sw = l15 & 7;

    stage(0, 0);
    asm volatile("s_waitcnt vmcnt(0)" ::: "memory");
    __builtin_amdgcn_s_barrier();

#pragma unroll 2
    for (int kt = 0; kt < NKT; ++kt) {
        const int cur = kt & 1;
        const bool st = (kt + 1) < NKT;
        if (st) stage(kt + 1, cur ^ 1);      // issue next tile's loads FIRST

        const __hip_bfloat16* A = &lds[cur][0];
        const __hip_bfloat16* B = &lds[cur][8192];
#pragma unroll
        for (int ks = 0; ks < 2; ++ks) {
            const int kc = ((ks * 4 + quad) ^ sw) * 8;  // swizzled chunk offset
            short8 af[4], bf[4];
#pragma unroll
            for (int im = 0; im < 4; ++im)
                af[im] = *(const short8*)&A[(wr * 64 + im * 16 + l15) * 64 + kc];
#pragma unroll
            for (int in = 0; in < 4; ++in)
                bf[in] = *(const short8*)&B[(wc * 64 + in * 16 + l15) * 64 + kc];
#pragma unroll
            for (int im = 0; im < 4; ++im)
#pragma unroll
                for (int in = 0; in < 4; ++in)
                    acc[im][in] = __builtin_amdgcn_mfma_f32_16x16x32_bf16(
                        af[im], bf[in], acc[im][in], 0, 0, 0);
        }

        if (st) {
            asm volatile("s_waitcnt vmcnt(0)" ::: "memory");
            __builtin_amdgcn_s_barrier();
        }
    }

    // epilogue: out[b][p][i][j] = sqrt(clip(s3 - 2C + psq)), s3 = 3x3 box of s
#pragma unroll
    for (int in = 0; in < 4; ++in) {
        int mm = n0 + wc * 64 + in * 16 + l15;
        int bb = mm / 676, rr = mm % 676, ii = rr / WOUT, jj = rr % WOUT;
        const float* sb = s + bb * HWIN + ii * WIN + jj;
        float s3v = 0.f;
#pragma unroll
        for (int di = 0; di < 3; ++di)
#pragma unroll
            for (int dj = 0; dj < 3; ++dj) s3v += sb[di * WIN + dj];
        float* ob = out + (size_t)bb * (NPROT * 676) + rr;
#pragma unroll
        for (int im = 0; im < 4; ++im) {
            int pbase_ = m0 + wr * 64 + im * 16 + quad * 4;
#pragma unroll
            for (int r = 0; r < 4; ++r) {
                int p = pbase_ + r;
                float d2 = s3v - 2.f * acc[im][in][r] + psq[p];
                ob[(size_t)p * 676] = sqrtf(fmaxf(d2, 1e-14f));
            }
        }
    }
}

// ---- fallback (only if ws too small): direct fp32 ----
__global__ void naive_kernel(const float* __restrict__ x,
                             const float* __restrict__ proto,
                             float* __restrict__ out) {
    __shared__ float patch[KTOT];
    int m = blockIdx.x;
    int b = m / 676, rr = m % 676, i = rr / WOUT, j = rr % WOUT;
    int c = threadIdx.x;
    const float* xb = x + (((size_t)b * CIN + c) * HIN + i) * WIN + j;
    for (int t = 0; t < 9; ++t) patch[c * 9 + t] = xb[(t / 3) * WIN + (t % 3)];
    __syncthreads();
    for (int pp = threadIdx.x; pp < NPROT; pp += 256) {
        const float* pr = proto + (size_t)pp * KTOT;
        float acc = 0.f;
        for (int k = 0; k < KTOT; ++k) { float d = patch[k] - pr[k]; acc += d * d; }
        out[((size_t)b * NPROT + pp) * 676 + rr] = sqrtf(fmaxf(acc, 1e-14f));
    }
}

extern "C" void kernel_launch(void* const* d_in, const int* in_sizes, int n_in,
                              void* d_out, int out_size, void* d_ws, size_t ws_size,
                              hipStream_t stream) {
    const float* x = (const float*)d_in[0];
    const float* proto = (const float*)d_in[1];
    float* out = (float*)d_out;

    if (ws_size < WS_NEED) {
        naive_kernel<<<MTOT, 256, 0, stream>>>(x, proto, out);
        return;
    }

    char* ws = (char*)d_ws;
    __hip_bfloat16* xT  = (__hip_bfloat16*)(ws + OFF_XT);
    __hip_bfloat16* pTT = (__hip_bfloat16*)(ws + OFF_PTT);
    float* s   = (float*)(ws + OFF_S);
    float* psq = (float*)(ws + OFF_PSQ);

    prep_kernel<<<dim3(800 + NPROT), 256, 0, stream>>>(x, proto, xT, pTT, s, psq);
    gemm_kernel<<<dim3(169, 8), 256, 0, stream>>>(xT, pTT, s, psq, out);
}

// Round 9
// 192.081 us; speedup vs baseline: 1.3829x; 1.2582x over previous
//
#include <hip/hip_runtime.h>
#include <hip/hip_bf16.h>
#include <math.h>

// Problem constants
#define BATCH 32
#define CIN   256
#define HIN   28
#define WIN   28
#define NPROT 1024
#define HOUT  26
#define WOUT  26
#define MTOT  (BATCH*HOUT*WOUT)   // 21632 = 169*128
#define HWIN  (HIN*WIN)           // 784
#define KTOT  (CIN*9)             // 2304
#define NKT   18                  // K-tiles of 128 fp8: 9 taps x 2 halves

typedef __attribute__((ext_vector_type(8))) int   i32x8;
typedef __attribute__((ext_vector_type(4))) int   i32x4;
typedef __attribute__((ext_vector_type(4))) float f32x4;

// ---- workspace layout (bytes), fp8 operands ----
// xT  : [32][784][256] fp8 = 6,422,528
// pTT : [9][1024][256] fp8 = 2,359,296
// s   : [32*784] f32       =   100,352
// psq : [1024] f32         =     4,096
#define OFF_XT  ((size_t)0)
#define OFF_PTT ((size_t)6422528)
#define OFF_S   ((size_t)8781824)
#define OFF_PSQ ((size_t)8882176)
#define WS_NEED ((size_t)8886272)

__device__ __forceinline__ void gload16(const void* g, void* l) {
    __builtin_amdgcn_global_load_lds((__attribute__((address_space(1))) void*)g,
                                     (__attribute__((address_space(3))) void*)l,
                                     16, 0, 0);
}

// ---- P1+P2 merged: one launch.
// blocks [0,800):   x NCHW fp32 -> NHWC fp8 e4m3 + per-pixel sum-sq (fp32)
// blocks [800,1824): prototypes OIHW fp32 -> [tap][p][c] fp8 + ||p||^2 (fp32)
__global__ __launch_bounds__(256)
void prep_kernel(const float* __restrict__ x, const float* __restrict__ proto,
                 unsigned char* __restrict__ xT, unsigned char* __restrict__ pTT,
                 float* __restrict__ s, float* __restrict__ psq) {
    const int bid = blockIdx.x;
    if (bid < 800) {
        // ---- xpose: 32 hw x 256 c tile; fp32 LDS tile, rotate-XOR swizzle ----
        __shared__ float tile[32 * 256];          // 32 KB
        __shared__ float red[32][33];
        __shared__ float red2[8][33];
        const int tid = threadIdx.x;
        const int b = bid / 25, hw0 = (bid % 25) * 32;
        const int i = tid & 7, cr = tid >> 3;
        const float* xb = x + (size_t)b * CIN * HWIN;
        const bool full = (hw0 + 32 <= HWIN);
        float sq[4] = {0.f, 0.f, 0.f, 0.f};
#pragma unroll
        for (int q = 0; q < 8; ++q) {
            const int c = q * 32 + cr;
            const int hw = hw0 + i * 4;
            float4 v;
            if (full) {
                v = *(const float4*)&xb[(size_t)c * HWIN + hw];
            } else {
                v.x = (hw + 0 < HWIN) ? xb[(size_t)c * HWIN + hw + 0] : 0.f;
                v.y = (hw + 1 < HWIN) ? xb[(size_t)c * HWIN + hw + 1] : 0.f;
                v.z = (hw + 2 < HWIN) ? xb[(size_t)c * HWIN + hw + 2] : 0.f;
                v.w = (hw + 3 < HWIN) ? xb[(size_t)c * HWIN + hw + 3] : 0.f;
            }
            const int cq = (c >> 3), c7 = c & 7;
            float vv[4] = {v.x, v.y, v.z, v.w};
#pragma unroll
            for (int d = 0; d < 4; ++d) {
                const int hwl = i * 4 + d;
                const int rot = ((hwl >> 2) | (hwl << 3)) & 31;
                tile[hwl * 256 + ((cq ^ rot) << 3) + c7] = vv[d];
                sq[d] += vv[d] * vv[d];
            }
        }
#pragma unroll
        for (int d = 0; d < 4; ++d) red[cr][i * 4 + d] = sq[d];
        __syncthreads();

        const int v2 = tid & 31, u = tid >> 5;
        {
            float part = 0.f;
#pragma unroll
            for (int j = 0; j < 4; ++j) part += red[u + 8 * j][v2];
            red2[u][v2] = part;
        }
        // fp8 NHWC writes: 8B per lane, 256B contiguous per half-wave row
#pragma unroll
        for (int w = 0; w < 4; ++w) {
            const int hwl = w * 8 + u;
            const int hw = hw0 + hwl;
            if (hw < HWIN) {
                const int rot = ((hwl >> 2) | (hwl << 3)) & 31;
                const float* g = &tile[hwl * 256 + ((v2 ^ rot) << 3)];
                float fa[8];
                *(float4*)&fa[0] = *(const float4*)g;
                *(float4*)&fa[4] = *(const float4*)(g + 4);
                int d0 = __builtin_amdgcn_cvt_pk_fp8_f32(fa[0], fa[1], 0, 0);
                d0     = __builtin_amdgcn_cvt_pk_fp8_f32(fa[2], fa[3], d0, 1);
                int d1 = __builtin_amdgcn_cvt_pk_fp8_f32(fa[4], fa[5], 0, 0);
                d1     = __builtin_amdgcn_cvt_pk_fp8_f32(fa[6], fa[7], d1, 1);
                int2 o; o.x = d0; o.y = d1;
                *(int2*)&xT[((size_t)b * HWIN + hw) * CIN + v2 * 8] = o;
            }
        }
        __syncthreads();
        if (u == 0) {
            const int hw = hw0 + v2;
            if (hw < HWIN) {
                float a = 0.f;
#pragma unroll
                for (int k = 0; k < 8; ++k) a += red2[k][v2];
                s[b * HWIN + hw] = a;
            }
        }
    } else {
        // ---- ppose ----
        const int p = bid - 800, c = threadIdx.x;
        const float* pp = proto + ((size_t)p * CIN + c) * 9;
        float v[9]; float ss = 0.f;
#pragma unroll
        for (int t = 0; t < 9; ++t) { v[t] = pp[t]; ss += v[t] * v[t]; }
#pragma unroll
        for (int t = 0; t < 9; ++t) {
            int q8 = __builtin_amdgcn_cvt_pk_fp8_f32(v[t], 0.f, 0, 0);
            pTT[((size_t)t * NPROT + p) * CIN + c] = (unsigned char)(q8 & 0xff);
        }
        for (int o = 32; o > 0; o >>= 1) ss += __shfl_down(ss, o, 64);
        __shared__ float redp[4];
        if ((c & 63) == 0) redp[c >> 6] = ss;
        __syncthreads();
        if (c == 0) psq[p] = redp[0] + redp[1] + redp[2] + redp[3];
    }
}

// ---- G: implicit-GEMM MX-fp8 MFMA (16x16x128, scales=1.0), 2-deep
// issue-early pipeline. Byte-level geometry IDENTICAL to the verified R3
// bf16 kernel (128 rows x 128B per tile-matrix, chunk^(row&7) swizzle,
// 0 bank conflicts), but each 128B row now holds 128 fp8 k-elements
// instead of 64 bf16 -> NKT 36->18: MFMA cycles -56%, ds_read/staging/
// barriers/drains all -50%.
// D[p][m] = sum_k proto[p][k] * patch[m][k]
// Operand frag (16x16x128 f8f6f4): row = lane&15, k = (lane>>4)*32 + j,
// j in [0,32) over 8 consecutive dwords (two swizzled 16B LDS chunks).
// C/D layout shape-determined (m121-128) == 16x16x32: col=lane&15,
// row=(lane>>4)*4+reg -> epilogue unchanged from R3.
__global__ __launch_bounds__(256, 2)
void gemm_kernel(const unsigned char* __restrict__ xT,
                 const unsigned char* __restrict__ pTT,
                 const float* __restrict__ s,
                 const float* __restrict__ psq,
                 float* __restrict__ out) {
    __shared__ unsigned char lds[2][32768];  // [buf][ A:0..16383 | B:16384..32767 ]
    const int tid = threadIdx.x, wave = tid >> 6, lane = tid & 63;
    const int n0 = blockIdx.x * 128;  // m (image-pos) tile base
    const int m0 = blockIdx.y * 128;  // p tile base
    const int lrow = lane >> 3;
    const int lcol = ((lane & 7) ^ lrow) * 16;  // pre-swizzled source chunk (BYTES)

    int xbase[4], pbase[4];
#pragma unroll
    for (int q = 0; q < 4; ++q) {
        int rl = wave * 32 + q * 8 + lrow;
        int mm = n0 + rl;
        int bb = mm / 676, rr = mm % 676, ii = rr / WOUT, jj = rr % WOUT;
        xbase[q] = (bb * HWIN + ii * WIN + jj) * CIN + lcol;
        pbase[q] = (m0 + rl) * CIN + lcol;
    }

    // stage K-tile kt (128 fp8 k-elts) into buffer buf: 8 gloads per wave
    auto stage = [&](int kt, int buf) {
        const int tap = kt >> 1, cc = (kt & 1) * 128;
        const unsigned char* srcP = pTT + (size_t)tap * (NPROT * CIN) + cc;
        const unsigned char* srcX = xT + ((tap / 3) * WIN + (tap % 3)) * CIN + cc;
        unsigned char* base = &lds[buf][0];
#pragma unroll
        for (int q = 0; q < 4; ++q) {
            gload16(srcP + pbase[q], base + (wave * 32 + q * 8) * 128);
            gload16(srcX + xbase[q], base + 16384 + (wave * 32 + q * 8) * 128);
        }
    };

    f32x4 acc[4][4];
#pragma unroll
    for (int a = 0; a < 4; ++a)
#pragma unroll
        for (int b = 0; b < 4; ++b) acc[a][b] = (f32x4){0.f, 0.f, 0.f, 0.f};

    const int wr = wave >> 1, wc = wave & 1;   // wave 2x2: wr->p dir, wc->m dir
    const int quad = lane >> 4, l15 = lane & 15;
    const int sw = l15 & 7;                    // row&7 (row bases are %8==0)
    const int c0 = (2 * quad) ^ sw, c1 = (2 * quad + 1) ^ sw;  // chunk slots

    stage(0, 0);
    asm volatile("s_waitcnt vmcnt(0)" ::: "memory");
    __builtin_amdgcn_s_barrier();

#pragma unroll 2
    for (int kt = 0; kt < NKT; ++kt) {
        const int cur = kt & 1;
        const bool st = (kt + 1) < NKT;
        if (st) stage(kt + 1, cur ^ 1);      // issue next tile's loads FIRST

        const unsigned char* A = &lds[cur][0];
        const unsigned char* B = &lds[cur][16384];
        i32x8 af[4], bf[4];
#pragma unroll
        for (int im = 0; im < 4; ++im) {
            const int rb = (wr * 64 + im * 16 + l15) * 128;
            i32x4 lo = *(const i32x4*)&A[rb + c0 * 16];
            i32x4 hi = *(const i32x4*)&A[rb + c1 * 16];
            af[im][0] = lo[0]; af[im][1] = lo[1]; af[im][2] = lo[2]; af[im][3] = lo[3];
            af[im][4] = hi[0]; af[im][5] = hi[1]; af[im][6] = hi[2]; af[im][7] = hi[3];
        }
#pragma unroll
        for (int in = 0; in < 4; ++in) {
            const int rb = (wc * 64 + in * 16 + l15) * 128;
            i32x4 lo = *(const i32x4*)&B[rb + c0 * 16];
            i32x4 hi = *(const i32x4*)&B[rb + c1 * 16];
            bf[in][0] = lo[0]; bf[in][1] = lo[1]; bf[in][2] = lo[2]; bf[in][3] = lo[3];
            bf[in][4] = hi[0]; bf[in][5] = hi[1]; bf[in][6] = hi[2]; bf[in][7] = hi[3];
        }
#pragma unroll
        for (int im = 0; im < 4; ++im)
#pragma unroll
            for (int in = 0; in < 4; ++in)
                acc[im][in] = __builtin_amdgcn_mfma_scale_f32_16x16x128_f8f6f4(
                    af[im], bf[in], acc[im][in],
                    0 /*cbsz: A=fp8 e4m3*/, 0 /*blgp: B=fp8 e4m3*/,
                    0, 127 /*scale A = 2^0*/, 0, 127 /*scale B = 2^0*/);

        if (st) {
            asm volatile("s_waitcnt vmcnt(0)" ::: "memory");
            __builtin_amdgcn_s_barrier();
        }
    }

    // epilogue: out[b][p][i][j] = sqrt(clip(s3 - 2C + psq)), s3 = 3x3 box of s
#pragma unroll
    for (int in = 0; in < 4; ++in) {
        int mm = n0 + wc * 64 + in * 16 + l15;
        int bb = mm / 676, rr = mm % 676, ii = rr / WOUT, jj = rr % WOUT;
        const float* sb = s + bb * HWIN + ii * WIN + jj;
        float s3v = 0.f;
#pragma unroll
        for (int di = 0; di < 3; ++di)
#pragma unroll
            for (int dj = 0; dj < 3; ++dj) s3v += sb[di * WIN + dj];
        float* ob = out + (size_t)bb * (NPROT * 676) + rr;
#pragma unroll
        for (int im = 0; im < 4; ++im) {
            int pbase_ = m0 + wr * 64 + im * 16 + quad * 4;
#pragma unroll
            for (int r = 0; r < 4; ++r) {
                int p = pbase_ + r;
                float d2 = s3v - 2.f * acc[im][in][r] + psq[p];
                ob[(size_t)p * 676] = sqrtf(fmaxf(d2, 1e-14f));
            }
        }
    }
}

// ---- fallback (only if ws too small): direct fp32 ----
__global__ void naive_kernel(const float* __restrict__ x,
                             const float* __restrict__ proto,
                             float* __restrict__ out) {
    __shared__ float patch[KTOT];
    int m = blockIdx.x;
    int b = m / 676, rr = m % 676, i = rr / WOUT, j = rr % WOUT;
    int c = threadIdx.x;
    const float* xb = x + (((size_t)b * CIN + c) * HIN + i) * WIN + j;
    for (int t = 0; t < 9; ++t) patch[c * 9 + t] = xb[(t / 3) * WIN + (t % 3)];
    __syncthreads();
    for (int pp = threadIdx.x; pp < NPROT; pp += 256) {
        const float* pr = proto + (size_t)pp * KTOT;
        float acc = 0.f;
        for (int k = 0; k < KTOT; ++k) { float d = patch[k] - pr[k]; acc += d * d; }
        out[((size_t)b * NPROT + pp) * 676 + rr] = sqrtf(fmaxf(acc, 1e-14f));
    }
}

extern "C" void kernel_launch(void* const* d_in, const int* in_sizes, int n_in,
                              void* d_out, int out_size, void* d_ws, size_t ws_size,
                              hipStream_t stream) {
    const float* x = (const float*)d_in[0];
    const float* proto = (const float*)d_in[1];
    float* out = (float*)d_out;

    if (ws_size < WS_NEED) {
        naive_kernel<<<MTOT, 256, 0, stream>>>(x, proto, out);
        return;
    }

    char* ws = (char*)d_ws;
    unsigned char* xT  = (unsigned char*)(ws + OFF_XT);
    unsigned char* pTT = (unsigned char*)(ws + OFF_PTT);
    float* s   = (float*)(ws + OFF_S);
    float* psq = (float*)(ws + OFF_PSQ);

    prep_kernel<<<dim3(800 + NPROT), 256, 0, stream>>>(x, proto, xT, pTT, s, psq);
    gemm_kernel<<<dim3(169, 8), 256, 0, stream>>>(xT, pTT, s, psq, out);
}